// Round 5
// baseline (560.316 us; speedup 1.0000x reference)
//
#include <hip/hip_runtime.h>
#include <math.h>

#define D_MODEL 4096
#define NEXP    64
#define TOPK    8
#define NTOK    16384        // 4 * 4096
#define BLK_TOK 64
#define DC      64           // d per chunk
#define KSPLIT  4
#define KQ      (D_MODEL / KSPLIT)   // 1024 d per block
#define NCHUNK_Q (KQ / DC)           // 16
#define EPW     8            // experts per wave
#define NWAVE   (NEXP / EPW) // 8
#define NTHR    (NWAVE * 64) // 512

#define WT2_FLOATS (NEXP * D_MODEL)  // 262144 floats = 1 MB

typedef float v2f __attribute__((ext_vector_type(2)));

// WT2 layout: [g:8][d2:2048][j:8][p:2] where WT2[(((g*2048)+d2)*8+j)*2+p] = W[g*8+j][2*d2+p].
// Expert j's weights for consecutive d form an aligned pair -> SGPR pair feeding
// v_pk_fma_f32; 32 consecutive floats per 4-d group -> 2x s_load_dwordx16.
__global__ void transpose_w_kernel(const float* __restrict__ W, float* __restrict__ WT2) {
    int o = blockIdx.x * 256 + threadIdx.x;    // 262144 total
    int p  = o & 1;
    int j  = (o >> 1) & 7;
    int d2 = (o >> 4) & 2047;
    int g  = o >> 15;
    WT2[o] = W[(size_t)(g * 8 + j) * D_MODEL + 2 * d2 + p];
}

// Grid: 1024 blocks = 256 token-tiles x 4 K-quarters. 512 threads = 8 waves x 8 experts.
// NOTE: plain __launch_bounds__(512) — NO min-waves arg. Rounds 2/3 proved the
// min-waves hint drives hipcc into scratch spills (VGPR_Count 32 then 16, with
// 3.2 GB / 253 MB of excess WRITE). Round-0's identical body got 52 VGPR without
// it, which still fits 8 waves/SIMD (512/52 -> 9, cap 8) -> full occupancy anyway.
__global__ __launch_bounds__(NTHR)
void router_kernel(const float* __restrict__ x, const float* __restrict__ WT2,
                   float* __restrict__ Pacc) {
    // x tile: 2 buffers x [d4:16][f4-slot:64], 32 KB -> 4 blocks/CU (128 of 160 KB).
    // XOR swizzle slot = row ^ q (q == d4&7): reads contiguous-permuted (conflict-free
    // b128), writes spread across banks (measured: conflicts 1.47e7 -> ~1e5).
    __shared__ __align__(16) float lds[2 * 4096];

    const int tid  = threadIdx.x;
    const int lane = tid & 63;                                   // token within block
    const int g    = __builtin_amdgcn_readfirstlane(tid >> 6);   // wave id == expert group
    const int s    = blockIdx.x & 3;                             // K-quarter
    const int tok0 = (blockIdx.x >> 2) * BLK_TOK;
    const int kbase = s * KQ;

    // staging mapping: 64 rows (tokens) x 8 threads/row, 2 float4 each = 64 d
    const int row  = tid >> 3;
    const int q    = tid & 7;

    v2f acc2[EPW];
#pragma unroll
    for (int j = 0; j < EPW; ++j) acc2[j] = (v2f)0.f;

    float4 xr[2];
    const float* xbase = x + (size_t)(tok0 + row) * D_MODEL + kbase + q * 4;
    const float* wk    = WT2 + (g << 15);   // this wave's [2048][8][2] W slab (uniform)

    auto load_chunk = [&](int d0) {
#pragma unroll
        for (int j = 0; j < 2; ++j)
            xr[j] = *(const float4*)(xbase + d0 + j * 32);    // 8 f4/row = 128B contiguous
    };
    auto store_chunk = [&](int buf) {
#pragma unroll
        for (int j = 0; j < 2; ++j)
            *(float4*)&lds[buf * 4096 + (q + j * 8) * 256 + ((row ^ q) << 2)] = xr[j];
    };
    auto compute_chunk = [&](int buf, int kk) {
        const float* wc = wk + kbase * 8 + kk * (DC * 8);     // uniform -> s_load
        const float* xb = &lds[buf * 4096];
#pragma unroll 4
        for (int d4 = 0; d4 < DC / 4; ++d4) {
            const float4 xq = *(const float4*)(xb + d4 * 256 + (((lane ^ (d4 & 7))) << 2));
            const float* wd = wc + d4 * 32;                   // 32 floats = 2 d2 x 8e x 2p
            const v2f xlo = {xq.x, xq.y};
            const v2f xhi = {xq.z, xq.w};
#pragma unroll
            for (int j = 0; j < EPW; ++j)
                acc2[j] = __builtin_elementwise_fma(xlo, *(const v2f*)(wd + j * 2), acc2[j]);
#pragma unroll
            for (int j = 0; j < EPW; ++j)
                acc2[j] = __builtin_elementwise_fma(xhi, *(const v2f*)(wd + 16 + j * 2), acc2[j]);
        }
    };

    // prologue
    load_chunk(0);
    store_chunk(0);
    __syncthreads();

    for (int kk = 0; kk < NCHUNK_Q; ++kk) {
        if (kk + 1 < NCHUNK_Q) load_chunk((kk + 1) * DC);    // global loads in flight
        compute_chunk(kk & 1, kk);
        if (kk + 1 < NCHUNK_Q) store_chunk((kk + 1) & 1);    // other buffer: no read hazard
        __syncthreads();                                      // one barrier per chunk
    }

    // ---- epilogue: gather [64 tok][64 e] partials into LDS, atomic-accumulate ----
    float* lg = lds;                     // reuse; last compute read other buf; synced below
#pragma unroll
    for (int j = 0; j < EPW; ++j)
        lg[lane * 65 + g * EPW + j] = acc2[j].x + acc2[j].y;
    __syncthreads();

    for (int i = tid; i < BLK_TOK * 16; i += NTHR) {   // 1024 float4-groups, 2 per thread
        const int t  = i >> 4;
        const int e4 = (i & 15) << 2;
        const float* src = &lg[t * 65 + e4];
        float* dst = &Pacc[(size_t)(tok0 + t) * NEXP + e4];
#pragma unroll
        for (int c = 0; c < 4; ++c) atomicAdd(dst + c, src[c]);
    }
}

// Softmax + top-9 + flag on the complete logits in out_p; overwrite out_p with probs.
__global__ __launch_bounds__(256)
void finalize_kernel(float* out_p, float* __restrict__ out_w, float* __restrict__ out_i,
                     int* __restrict__ cnt, int* __restrict__ list) {
    __shared__ float lg[BLK_TOK * 65];   // [64][65] logits/probs
    const int tid  = threadIdx.x;
    const int tok0 = blockIdx.x * BLK_TOK;

    for (int i = tid; i < BLK_TOK * 16; i += 256) {          // load tile into LDS
        const int t  = i >> 4;
        const int e4 = (i & 15) << 2;
        const float4 a = *(const float4*)&out_p[(size_t)(tok0 + t) * NEXP + e4];
        float* dst = &lg[t * 65 + e4];
        dst[0] = a.x; dst[1] = a.y; dst[2] = a.z; dst[3] = a.w;
    }
    __syncthreads();

    if (tid < 64) {                      // wave 0: one token per lane
        const int tok = tok0 + tid;
        float p[64];
        float m = -INFINITY;
#pragma unroll
        for (int e = 0; e < 64; ++e) {
            p[e] = lg[tid * 65 + e];
            m = fmaxf(m, p[e]);
        }
        float z = 0.f;
#pragma unroll
        for (int e = 0; e < 64; ++e) {
            p[e] = __expf(p[e] - m);
            z += p[e];
        }
        const float rz = 1.f / z;
#pragma unroll
        for (int e = 0; e < 64; ++e) {
            p[e] *= rz;
            lg[tid * 65 + e] = p[e];    // publish probs for cooperative store
        }

        // branch-free top-9 (strict > => lowest index on ties, matching lax.top_k)
        float tv[9]; int ti[9];
#pragma unroll
        for (int k = 0; k < 9; ++k) { tv[k] = -1.f; ti[k] = 0; }
        for (int e = 0; e < 64; ++e) {
            float v = p[e]; int idx = e;
#pragma unroll
            for (int k = 0; k < 9; ++k) {
                const bool gt = v > tv[k];
                const float nv = gt ? v : tv[k];
                const int   ni = gt ? idx : ti[k];
                const float ov = gt ? tv[k] : v;
                const int   oi = gt ? ti[k] : idx;
                tv[k] = nv; ti[k] = ni; v = ov; idx = oi;
            }
        }
        // ambiguity flag: adjacent relative gap below 2e-4 (fp32 err sigma ~3e-6 => 66x margin)
        int flag = 0;
#pragma unroll
        for (int k = 0; k < 8; ++k)
            if (tv[k] - tv[k + 1] <= tv[k] * 2e-4f + 1e-12f) flag = 1;
        if (flag) {
            int sidx = atomicAdd(cnt, 1);
            list[sidx] = tok;
        }

        float s8 = 0.f;
#pragma unroll
        for (int k = 0; k < 8; ++k) s8 += tv[k];
        const float denom = s8 + 1e-9f;
#pragma unroll
        for (int k = 0; k < 8; ++k) {
            out_w[tok * TOPK + k] = tv[k] / denom;
            out_i[tok * TOPK + k] = (float)ti[k];
        }
    }
    __syncthreads();

    // cooperative coalesced probs store: 64 tok x 16 float4
    for (int i = tid; i < BLK_TOK * 16; i += 256) {
        const int t  = i >> 4;
        const int e4 = (i & 15) << 2;
        const float* src = &lg[t * 65 + e4];
        *(float4*)&out_p[(size_t)(tok0 + t) * NEXP + e4] =
            make_float4(src[0], src[1], src[2], src[3]);
    }
}

// Repair: iterate compacted flagged-token list, recompute logits in fp64, rewrite w/i.
// 256 threads: expert = tid&63, d-quarter = tid>>6; LDS-reduce 4 partials.
__global__ __launch_bounds__(256)
void repair_kernel(const float* __restrict__ x, const float* __restrict__ W,
                   const int* __restrict__ cnt, const int* __restrict__ list,
                   float* __restrict__ out_w, float* __restrict__ out_i) {
    __shared__ float  xs[D_MODEL];   // 16 KB
    __shared__ double ls[4][NEXP];   // 2 KB
    const int tid = threadIdx.x;
    const int e   = tid & 63;
    const int w4  = tid >> 6;        // d-quarter 0..3
    const int n   = cnt[0];

    for (int i = blockIdx.x; i < n; i += gridDim.x) {
        const int tok = list[i];
        __syncthreads();             // protect xs reuse across iterations
        const float4* xsrc = (const float4*)(x + (size_t)tok * D_MODEL);
        for (int v = tid; v < D_MODEL / 4; v += 256)
            ((float4*)xs)[v] = xsrc[v];
        __syncthreads();

        const float* wrow = W + (size_t)e * D_MODEL + w4 * (D_MODEL / 4);
        const float* xrow = xs + w4 * (D_MODEL / 4);
        double s0 = 0., s1 = 0., s2 = 0., s3 = 0.;
        for (int d = 0; d < D_MODEL / 4; d += 4) {
            const float4 wv = *(const float4*)(wrow + d);
            const float4 xv = *(const float4*)(xrow + d);
            s0 += (double)xv.x * (double)wv.x;
            s1 += (double)xv.y * (double)wv.y;
            s2 += (double)xv.z * (double)wv.z;
            s3 += (double)xv.w * (double)wv.w;
        }
        ls[w4][e] = (s0 + s1) + (s2 + s3);
        __syncthreads();

        if (tid == 0) {
            double lsum[64];
            for (int k = 0; k < 64; ++k)
                lsum[k] = (ls[0][k] + ls[1][k]) + (ls[2][k] + ls[3][k]);
            double m = -1e300;
            for (int k = 0; k < 64; ++k) m = lsum[k] > m ? lsum[k] : m;
            double p[64], Z = 0.;
            for (int k = 0; k < 64; ++k) { p[k] = exp(lsum[k] - m); Z += p[k]; }
            for (int k = 0; k < 64; ++k) p[k] /= Z;

            double tv[8]; int ti[8];
            for (int k = 0; k < 8; ++k) { tv[k] = -1.; ti[k] = 0; }
            for (int k = 0; k < 64; ++k) {
                double v = p[k]; int idx = k;
                for (int u = 0; u < 8; ++u) {
                    const bool gt = v > tv[u];
                    const double nv = gt ? v : tv[u];
                    const int    ni = gt ? idx : ti[u];
                    const double ov = gt ? tv[u] : v;
                    const int    oi = gt ? ti[u] : idx;
                    tv[u] = nv; ti[u] = ni; v = ov; idx = oi;
                }
            }
            double s8 = 0.;
            for (int k = 0; k < 8; ++k) s8 += tv[k];
            const double denom = s8 + 1e-9;
            for (int k = 0; k < 8; ++k) {
                out_w[tok * TOPK + k] = (float)(tv[k] / denom);
                out_i[tok * TOPK + k] = (float)ti[k];
            }
        }
    }
}

extern "C" void kernel_launch(void* const* d_in, const int* in_sizes, int n_in,
                              void* d_out, int out_size, void* d_ws, size_t ws_size,
                              hipStream_t stream) {
    const float* x = (const float*)d_in[0];   // [4,4096,4096]
    const float* W = (const float*)d_in[1];   // [64,4096]

    // workspace layout identical to the proven round-0 kernel (~1.07 MB)
    float* WT2  = (float*)d_ws;                          // 1 MB
    int*   cnt  = (int*)((float*)d_ws + WT2_FLOATS);     // 1 int
    int*   list = cnt + 1;                               // up to 16384 ints

    float* out   = (float*)d_out;
    float* out_w = out;                       // [16384,8]
    float* out_i = out + NTOK * TOPK;         // [16384,8] (as float)
    float* out_p = out + 2 * NTOK * TOPK;     // [16384,64]; doubles as logit accumulator

    hipMemsetAsync(cnt, 0, sizeof(int), stream);
    hipMemsetAsync(out_p, 0, (size_t)NTOK * NEXP * sizeof(float), stream);
    transpose_w_kernel<<<WT2_FLOATS / 256, 256, 0, stream>>>(W, WT2);
    router_kernel<<<(NTOK / BLK_TOK) * KSPLIT, NTHR, 0, stream>>>(x, WT2, out_p);
    finalize_kernel<<<NTOK / BLK_TOK, 256, 0, stream>>>(out_p, out_w, out_i, cnt, list);
    repair_kernel<<<256, 256, 0, stream>>>(x, W, cnt, list, out_w, out_i);
}

// Round 6
// 555.368 us; speedup vs baseline: 1.0089x; 1.0089x over previous
//
#include <hip/hip_runtime.h>
#include <math.h>

#define D_MODEL 4096
#define NEXP    64
#define TOPK    8
#define NTOK    16384        // 4 * 4096
#define BLK_TOK 64
#define DC      64           // d per chunk
#define KSPLIT  4
#define KQ      (D_MODEL / KSPLIT)   // 1024 d per block
#define NCHUNK_Q (KQ / DC)           // 16
#define EPW     8            // experts per wave
#define NWAVE   (NEXP / EPW) // 8
#define NTHR    (NWAVE * 64) // 512

#define WT2_FLOATS (NEXP * D_MODEL)  // 262144 floats = 1 MB

// WT2 layout (round-0 proven): [g:8][d:4096][j:8], WT2[g][d][j] = W[g*8+j][d].
// Wave's W access is uniform -> s_load_dwordx16 x2 per 4-d group; inner FMA is
// v_fmac_f32 v, s, v (52 VGPR, no scratch — measured round 0).
// Also folds the two memsets: zeros out_p (4 floats/thread) and cnt.
__global__ void transpose_w_kernel(const float* __restrict__ W, float* __restrict__ WT2,
                                   float* __restrict__ out_p, int* __restrict__ cnt) {
    int o = blockIdx.x * 256 + threadIdx.x;    // 262144 total
    int j = o & 7;
    int d = (o >> 3) & (D_MODEL - 1);
    int g = o >> 15;
    WT2[o] = W[(size_t)(g * 8 + j) * D_MODEL + d];
    *(float4*)&out_p[(size_t)o * 4] = make_float4(0.f, 0.f, 0.f, 0.f);  // 1M floats total
    if (o == 0) *cnt = 0;
}

// Grid: 1024 blocks = 256 token-tiles x 4 K-quarters. 512 threads = 8 waves x 8 experts.
// Plain __launch_bounds__(512): R2/R3/R5 proved any min-waves hint OR the v2f packed
// body drives hipcc to scratch (VGPR 32/16/20, WRITE 3.2GB/253MB/174MB, occupancy
// capped 49%). This scalar body measured 52 VGPR scratch-free (R0) -> 8 waves/SIMD.
// 32 KB LDS -> 4 blocks/CU -> 32 waves/CU.
__global__ __launch_bounds__(NTHR)
void router_kernel(const float* __restrict__ x, const float* __restrict__ WT2,
                   float* __restrict__ Pacc) {
    // x tile: 2 buffers x [d4:16][f4-slot:64], 32 KB. XOR swizzle slot = row ^ q
    // (q == d4&7): reads contiguous-permuted (conflict-free b128), writes spread
    // across banks (measured: conflicts 1.47e7 -> ~1.3e5).
    __shared__ __align__(16) float lds[2 * 4096];

    const int tid  = threadIdx.x;
    const int lane = tid & 63;                                   // token within block
    const int g    = __builtin_amdgcn_readfirstlane(tid >> 6);   // wave id == expert group
    const int s    = blockIdx.x & 3;                             // K-quarter
    const int tok0 = (blockIdx.x >> 2) * BLK_TOK;
    const int kbase = s * KQ;

    // staging mapping: 64 rows (tokens) x 8 threads/row, 2 float4 each = 64 d
    const int row  = tid >> 3;
    const int q    = tid & 7;

    float acc[EPW];
#pragma unroll
    for (int j = 0; j < EPW; ++j) acc[j] = 0.f;

    float4 xr[2];
    const float* xbase = x + (size_t)(tok0 + row) * D_MODEL + kbase + q * 4;
    const float* wk    = WT2 + (g << 15);   // this wave's [4096][8] W slab (uniform addr)

    auto load_chunk = [&](int d0) {
#pragma unroll
        for (int j = 0; j < 2; ++j)
            xr[j] = *(const float4*)(xbase + d0 + j * 32);    // 8 f4/row = 128B contiguous
    };
    auto store_chunk = [&](int buf) {
#pragma unroll
        for (int j = 0; j < 2; ++j)
            *(float4*)&lds[buf * 4096 + (q + j * 8) * 256 + ((row ^ q) << 2)] = xr[j];
    };
    auto compute_chunk = [&](int buf, int kk) {
        const float* wc = wk + (kbase + kk * DC) * 8;         // uniform -> s_load
        const float* xb = &lds[buf * 4096];
#pragma unroll 4
        for (int d4 = 0; d4 < DC / 4; ++d4) {
            const float4 xq = *(const float4*)(xb + d4 * 256 + ((lane ^ (d4 & 7)) << 2));
            const float* wd = wc + d4 * 32;                   // 32 floats = 4d x 8e
#pragma unroll
            for (int dd = 0; dd < 4; ++dd) {
                const float xv = (dd == 0) ? xq.x : (dd == 1) ? xq.y : (dd == 2) ? xq.z : xq.w;
#pragma unroll
                for (int j = 0; j < 8; ++j)
                    acc[j] = fmaf(xv, wd[dd * 8 + j], acc[j]);   // v_fmac v, s, v
            }
        }
    };

    // prologue
    load_chunk(0);
    store_chunk(0);
    __syncthreads();

    for (int kk = 0; kk < NCHUNK_Q; ++kk) {
        if (kk + 1 < NCHUNK_Q) load_chunk((kk + 1) * DC);    // global loads in flight
        compute_chunk(kk & 1, kk);
        if (kk + 1 < NCHUNK_Q) store_chunk((kk + 1) & 1);    // other buffer: no read hazard
        __syncthreads();                                      // one barrier per chunk
    }

    // ---- epilogue: gather [64 tok][64 e] partials into LDS, atomic-accumulate ----
    float* lg = lds;                     // reuse; synced below
#pragma unroll
    for (int j = 0; j < EPW; ++j)
        lg[lane * 65 + g * EPW + j] = acc[j];
    __syncthreads();

    for (int i = tid; i < BLK_TOK * 16; i += NTHR) {   // 1024 float4-groups, 2 per thread
        const int t  = i >> 4;
        const int e4 = (i & 15) << 2;
        const float* src = &lg[t * 65 + e4];
        float* dst = &Pacc[(size_t)(tok0 + t) * NEXP + e4];
#pragma unroll
        for (int c = 0; c < 4; ++c) atomicAdd(dst + c, src[c]);
    }
}

// Softmax + top-9 + flag on the complete logits in out_p; overwrite out_p with probs.
__global__ __launch_bounds__(256)
void finalize_kernel(float* out_p, float* __restrict__ out_w, float* __restrict__ out_i,
                     int* __restrict__ cnt, int* __restrict__ list) {
    __shared__ float lg[BLK_TOK * 65];   // [64][65] logits/probs
    const int tid  = threadIdx.x;
    const int tok0 = blockIdx.x * BLK_TOK;

    for (int i = tid; i < BLK_TOK * 16; i += 256) {          // load tile into LDS
        const int t  = i >> 4;
        const int e4 = (i & 15) << 2;
        const float4 a = *(const float4*)&out_p[(size_t)(tok0 + t) * NEXP + e4];
        float* dst = &lg[t * 65 + e4];
        dst[0] = a.x; dst[1] = a.y; dst[2] = a.z; dst[3] = a.w;
    }
    __syncthreads();

    if (tid < 64) {                      // wave 0: one token per lane
        const int tok = tok0 + tid;
        float p[64];
        float m = -INFINITY;
#pragma unroll
        for (int e = 0; e < 64; ++e) {
            p[e] = lg[tid * 65 + e];
            m = fmaxf(m, p[e]);
        }
        float z = 0.f;
#pragma unroll
        for (int e = 0; e < 64; ++e) {
            p[e] = __expf(p[e] - m);
            z += p[e];
        }
        const float rz = 1.f / z;
#pragma unroll
        for (int e = 0; e < 64; ++e) {
            p[e] *= rz;
            lg[tid * 65 + e] = p[e];    // publish probs for cooperative store
        }

        // branch-free top-9 (strict > => lowest index on ties, matching lax.top_k)
        float tv[9]; int ti[9];
#pragma unroll
        for (int k = 0; k < 9; ++k) { tv[k] = -1.f; ti[k] = 0; }
        for (int e = 0; e < 64; ++e) {
            float v = p[e]; int idx = e;
#pragma unroll
            for (int k = 0; k < 9; ++k) {
                const bool gt = v > tv[k];
                const float nv = gt ? v : tv[k];
                const int   ni = gt ? idx : ti[k];
                const float ov = gt ? tv[k] : v;
                const int   oi = gt ? ti[k] : idx;
                tv[k] = nv; ti[k] = ni; v = ov; idx = oi;
            }
        }
        // ambiguity flag: adjacent relative gap below 2e-4 (fp32 err sigma ~3e-6 => 66x margin)
        int flag = 0;
#pragma unroll
        for (int k = 0; k < 8; ++k)
            if (tv[k] - tv[k + 1] <= tv[k] * 2e-4f + 1e-12f) flag = 1;
        if (flag) {
            int sidx = atomicAdd(cnt, 1);
            list[sidx] = tok;
        }

        float s8 = 0.f;
#pragma unroll
        for (int k = 0; k < 8; ++k) s8 += tv[k];
        const float denom = s8 + 1e-9f;
#pragma unroll
        for (int k = 0; k < 8; ++k) {
            out_w[tok * TOPK + k] = tv[k] / denom;
            out_i[tok * TOPK + k] = (float)ti[k];
        }
    }
    __syncthreads();

    // cooperative coalesced probs store: 64 tok x 16 float4
    for (int i = tid; i < BLK_TOK * 16; i += 256) {
        const int t  = i >> 4;
        const int e4 = (i & 15) << 2;
        const float* src = &lg[t * 65 + e4];
        *(float4*)&out_p[(size_t)(tok0 + t) * NEXP + e4] =
            make_float4(src[0], src[1], src[2], src[3]);
    }
}

// Repair: iterate compacted flagged-token list, recompute logits in fp64, rewrite w/i.
// 256 threads: expert = tid&63, d-quarter = tid>>6; LDS-reduce 4 partials.
__global__ __launch_bounds__(256)
void repair_kernel(const float* __restrict__ x, const float* __restrict__ W,
                   const int* __restrict__ cnt, const int* __restrict__ list,
                   float* __restrict__ out_w, float* __restrict__ out_i) {
    __shared__ float  xs[D_MODEL];   // 16 KB
    __shared__ double ls[4][NEXP];   // 2 KB
    const int tid = threadIdx.x;
    const int e   = tid & 63;
    const int w4  = tid >> 6;        // d-quarter 0..3
    const int n   = cnt[0];

    for (int i = blockIdx.x; i < n; i += gridDim.x) {
        const int tok = list[i];
        __syncthreads();             // protect xs reuse across iterations
        const float4* xsrc = (const float4*)(x + (size_t)tok * D_MODEL);
        for (int v = tid; v < D_MODEL / 4; v += 256)
            ((float4*)xs)[v] = xsrc[v];
        __syncthreads();

        const float* wrow = W + (size_t)e * D_MODEL + w4 * (D_MODEL / 4);
        const float* xrow = xs + w4 * (D_MODEL / 4);
        double s0 = 0., s1 = 0., s2 = 0., s3 = 0.;
        for (int d = 0; d < D_MODEL / 4; d += 4) {
            const float4 wv = *(const float4*)(wrow + d);
            const float4 xv = *(const float4*)(xrow + d);
            s0 += (double)xv.x * (double)wv.x;
            s1 += (double)xv.y * (double)wv.y;
            s2 += (double)xv.z * (double)wv.z;
            s3 += (double)xv.w * (double)wv.w;
        }
        ls[w4][e] = (s0 + s1) + (s2 + s3);
        __syncthreads();

        if (tid == 0) {
            double lsum[64];
            for (int k = 0; k < 64; ++k)
                lsum[k] = (ls[0][k] + ls[1][k]) + (ls[2][k] + ls[3][k]);
            double m = -1e300;
            for (int k = 0; k < 64; ++k) m = lsum[k] > m ? lsum[k] : m;
            double p[64], Z = 0.;
            for (int k = 0; k < 64; ++k) { p[k] = exp(lsum[k] - m); Z += p[k]; }
            for (int k = 0; k < 64; ++k) p[k] /= Z;

            double tv[8]; int ti[8];
            for (int k = 0; k < 8; ++k) { tv[k] = -1.; ti[k] = 0; }
            for (int k = 0; k < 64; ++k) {
                double v = p[k]; int idx = k;
                for (int u = 0; u < 8; ++u) {
                    const bool gt = v > tv[u];
                    const double nv = gt ? v : tv[u];
                    const int    ni = gt ? idx : ti[u];
                    const double ov = gt ? tv[u] : v;
                    const int    oi = gt ? ti[u] : idx;
                    tv[u] = nv; ti[u] = ni; v = ov; idx = oi;
                }
            }
            double s8 = 0.;
            for (int k = 0; k < 8; ++k) s8 += tv[k];
            const double denom = s8 + 1e-9;
            for (int k = 0; k < 8; ++k) {
                out_w[tok * TOPK + k] = (float)(tv[k] / denom);
                out_i[tok * TOPK + k] = (float)ti[k];
            }
        }
    }
}

extern "C" void kernel_launch(void* const* d_in, const int* in_sizes, int n_in,
                              void* d_out, int out_size, void* d_ws, size_t ws_size,
                              hipStream_t stream) {
    const float* x = (const float*)d_in[0];   // [4,4096,4096]
    const float* W = (const float*)d_in[1];   // [64,4096]

    // workspace layout identical to the proven round-0 kernel (~1.07 MB)
    float* WT2  = (float*)d_ws;                          // 1 MB
    int*   cnt  = (int*)((float*)d_ws + WT2_FLOATS);     // 1 int
    int*   list = cnt + 1;                               // up to 16384 ints

    float* out   = (float*)d_out;
    float* out_w = out;                       // [16384,8]
    float* out_i = out + NTOK * TOPK;         // [16384,8] (as float)
    float* out_p = out + 2 * NTOK * TOPK;     // [16384,64]; doubles as logit accumulator

    // transpose kernel also zeros out_p and cnt (saves two memset dispatches)
    transpose_w_kernel<<<WT2_FLOATS / 256, 256, 0, stream>>>(W, WT2, out_p, cnt);
    router_kernel<<<(NTOK / BLK_TOK) * KSPLIT, NTHR, 0, stream>>>(x, WT2, out_p);
    finalize_kernel<<<NTOK / BLK_TOK, 256, 0, stream>>>(out_p, out_w, out_i, cnt, list);
    repair_kernel<<<256, 256, 0, stream>>>(x, W, cnt, list, out_w, out_i);
}

// Round 8
// 538.674 us; speedup vs baseline: 1.0402x; 1.0310x over previous
//
#include <hip/hip_runtime.h>
#include <math.h>

#define D_MODEL 4096
#define NEXP    64
#define TOPK    8
#define NTOK    16384        // 4 * 4096
#define BLK_TOK 64
#define KSPLIT  4
#define KQ      (D_MODEL / KSPLIT)   // 1024 d per block
#define R_GRID  ((NTOK / BLK_TOK) * KSPLIT)  // 1024

#define W2_USHORTS (NEXP * D_MODEL * 2)      // 524288 ushorts = 1 MB (hi+lo bf16)

typedef __attribute__((ext_vector_type(8))) short bf16x8;   // 8 bf16 = 4 VGPRs
typedef __attribute__((ext_vector_type(4))) float f32x4;

// bf16 round-to-nearest-even of fp32 (manual: no hip_bf16 header dependency)
__device__ inline unsigned b16rne(float f) {
    unsigned u = __float_as_uint(f);
    return (u + 0x7FFFu + ((u >> 16) & 1u)) >> 16;   // low 16 bits valid
}

// W2 layout: [kb:512][e:64][h:2][i:8] bf16, kb = d>>3, i = d&7.
// W2[((kb*64+e)*2+h)*8+i] = bf16 of (h==0 ? hi : lo) part of W[e][kb*8+i].
// kb-row stride = 64*2*8 = 1024 ushorts. Also zeros out_p and cnt.
__global__ void transpose_w_kernel(const float* __restrict__ W, unsigned short* __restrict__ W2,
                                   float* __restrict__ out_p, int* __restrict__ cnt) {
    int o = blockIdx.x * 256 + threadIdx.x;    // 262144 = 512 kb x 64 e x 8 i
    int i  = o & 7;
    int e  = (o >> 3) & 63;
    int kb = o >> 9;
    float w = W[(size_t)e * D_MODEL + kb * 8 + i];
    unsigned hb = b16rne(w);
    float hf = __uint_as_float(hb << 16);
    unsigned lb = b16rne(w - hf);
    size_t base = ((size_t)(kb * 64 + e) * 2) * 8 + i;
    W2[base]     = (unsigned short)hb;
    W2[base + 8] = (unsigned short)lb;
    *(float4*)&out_p[(size_t)o * 4] = make_float4(0.f, 0.f, 0.f, 0.f);  // 1M floats
    if (o == 0) *cnt = 0;
}

// Grid: 1024 blocks = 256 token-tiles x 4 K-quarters; 256 threads = 4 waves.
// Wave w computes tokens [w*16, w*16+16) x all 64 experts over its K-quarter via
// 3-term bf16-split MFMA (hi*hi + hi*lo + lo*hi; fp32 accum; err sigma ~1.5e-5).
// R7 BUG (fixed): per-K-step B stride is 4 kb-rows = 4096 ushorts (32 d / 8 d-per-kb
// x 1024 ushorts/kb-row); R7 used 8192, walking W at 2x K rate + OOB on quarter 3
// -> scrambled logits. Frag maps (m89/m91-verified D; standard A/B): A row=lane&15,
// B col=lane&15, both k=(lane>>4)*8+i (any consistent bijection cancels A vs B);
// D col=lane&15, row=(lane>>4)*4+reg.
__global__ __launch_bounds__(256)
void router_kernel(const float* __restrict__ x, const unsigned short* __restrict__ W2,
                   float* __restrict__ Pacc) {
    __shared__ float lg[BLK_TOK * 65];   // epilogue gather only (16.6 KB)

    const int tid  = threadIdx.x;
    const int lane = tid & 63;
    const int wv   = __builtin_amdgcn_readfirstlane(tid >> 6);   // token stripe 0..3

    // XCD swizzle (1024 % 8 == 0 -> bijective): a tile's 4 K-split siblings
    // (consecutive nb) land on the same XCD -> atomic partials stay in one L2.
    const int nb   = (blockIdx.x & 7) * (R_GRID / 8) + (blockIdx.x >> 3);
    const int s    = nb & 3;                             // K-quarter
    const int tok0 = (nb >> 2) * BLK_TOK;
    const int kbase = s * KQ;

    const int l15 = lane & 15;
    const int kg  = lane >> 4;                           // k-group 0..3

    f32x4 acc[4];
#pragma unroll
    for (int nt = 0; nt < 4; ++nt) acc[nt] = (f32x4)0.f;

    const float* xrow = x + (size_t)(tok0 + wv * 16 + l15) * D_MODEL + kbase + kg * 8;
    // per-thread B base: entry (kb0 = kbase/8 + kg, e = l15), 16 ushorts/entry
    const unsigned short* wbase = W2 + ((size_t)(((kbase >> 3) + kg) * 64 + l15) * 2) * 8;

    for (int ks = 0; ks < KQ / 32; ++ks) {               // 32 K-steps of 32 d
        const float4 xa = *(const float4*)(xrow + ks * 32);
        const float4 xb = *(const float4*)(xrow + ks * 32 + 4);

        union { unsigned u[4]; bf16x8 v; } Ahi, Alo;
#pragma unroll
        for (int p = 0; p < 4; ++p) {
            const float f0 = (p == 0) ? xa.x : (p == 1) ? xa.z : (p == 2) ? xb.x : xb.z;
            const float f1 = (p == 0) ? xa.y : (p == 1) ? xa.w : (p == 2) ? xb.y : xb.w;
            const unsigned h0 = b16rne(f0), h1 = b16rne(f1);
            Ahi.u[p] = h0 | (h1 << 16);
            const float l0 = f0 - __uint_as_float(h0 << 16);
            const float l1 = f1 - __uint_as_float(h1 << 16);
            Alo.u[p] = b16rne(l0) | (b16rne(l1) << 16);
        }

        const unsigned short* wk = wbase + (size_t)ks * 4096;   // +4 kb-rows (FIX)
#pragma unroll
        for (int nt = 0; nt < 4; ++nt) {
            const unsigned short* wp = wk + nt * 256;    // +16 experts
            const bf16x8 bhi = *(const bf16x8*)(wp);
            const bf16x8 blo = *(const bf16x8*)(wp + 8);
            acc[nt] = __builtin_amdgcn_mfma_f32_16x16x32_bf16(Ahi.v, bhi, acc[nt], 0, 0, 0);
            acc[nt] = __builtin_amdgcn_mfma_f32_16x16x32_bf16(Ahi.v, blo, acc[nt], 0, 0, 0);
            acc[nt] = __builtin_amdgcn_mfma_f32_16x16x32_bf16(Alo.v, bhi, acc[nt], 0, 0, 0);
        }
    }

    // ---- epilogue: D frag -> [64 tok][64 e] LDS tile, atomic-accumulate ----
#pragma unroll
    for (int nt = 0; nt < 4; ++nt)
#pragma unroll
        for (int r = 0; r < 4; ++r)
            lg[(wv * 16 + kg * 4 + r) * 65 + nt * 16 + l15] = acc[nt][r];
    __syncthreads();

    for (int i = tid; i < BLK_TOK * 16; i += 256) {      // 1024 float4-groups
        const int t  = i >> 4;
        const int e4 = (i & 15) << 2;
        const float* src = &lg[t * 65 + e4];
        float* dst = &Pacc[(size_t)(tok0 + t) * NEXP + e4];
#pragma unroll
        for (int c = 0; c < 4; ++c) atomicAdd(dst + c, src[c]);
    }
}

// Softmax + top-9 + flag on the complete logits in out_p; overwrite out_p with probs.
__global__ __launch_bounds__(256)
void finalize_kernel(float* out_p, float* __restrict__ out_w, float* __restrict__ out_i,
                     int* __restrict__ cnt, int* __restrict__ list) {
    __shared__ float lg[BLK_TOK * 65];   // [64][65] logits/probs
    const int tid  = threadIdx.x;
    const int tok0 = blockIdx.x * BLK_TOK;

    for (int i = tid; i < BLK_TOK * 16; i += 256) {          // load tile into LDS
        const int t  = i >> 4;
        const int e4 = (i & 15) << 2;
        const float4 a = *(const float4*)&out_p[(size_t)(tok0 + t) * NEXP + e4];
        float* dst = &lg[t * 65 + e4];
        dst[0] = a.x; dst[1] = a.y; dst[2] = a.z; dst[3] = a.w;
    }
    __syncthreads();

    if (tid < 64) {                      // wave 0: one token per lane
        const int tok = tok0 + tid;
        float p[64];
        float m = -INFINITY;
#pragma unroll
        for (int e = 0; e < 64; ++e) {
            p[e] = lg[tid * 65 + e];
            m = fmaxf(m, p[e]);
        }
        float z = 0.f;
#pragma unroll
        for (int e = 0; e < 64; ++e) {
            p[e] = __expf(p[e] - m);
            z += p[e];
        }
        const float rz = 1.f / z;
#pragma unroll
        for (int e = 0; e < 64; ++e) {
            p[e] *= rz;
            lg[tid * 65 + e] = p[e];    // publish probs for cooperative store
        }

        // branch-free top-9 (strict > => lowest index on ties, matching lax.top_k)
        float tv[9]; int ti[9];
#pragma unroll
        for (int k = 0; k < 9; ++k) { tv[k] = -1.f; ti[k] = 0; }
        for (int e = 0; e < 64; ++e) {
            float v = p[e]; int idx = e;
#pragma unroll
            for (int k = 0; k < 9; ++k) {
                const bool gt = v > tv[k];
                const float nv = gt ? v : tv[k];
                const int   ni = gt ? idx : ti[k];
                const float ov = gt ? tv[k] : v;
                const int   oi = gt ? ti[k] : idx;
                tv[k] = nv; ti[k] = ni; v = ov; idx = oi;
            }
        }
        // ambiguity flag: adjacent relative gap below 4e-4.
        // bf16-split logit err sigma ~1.5e-5 -> prob-gap err ~3e-5*p; 4e-4 > 13 sigma.
        int flag = 0;
#pragma unroll
        for (int k = 0; k < 8; ++k)
            if (tv[k] - tv[k + 1] <= tv[k] * 4e-4f + 1e-9f) flag = 1;
        if (flag) {
            int sidx = atomicAdd(cnt, 1);
            list[sidx] = tok;
        }

        float s8 = 0.f;
#pragma unroll
        for (int k = 0; k < 8; ++k) s8 += tv[k];
        const float denom = s8 + 1e-9f;
#pragma unroll
        for (int k = 0; k < 8; ++k) {
            out_w[tok * TOPK + k] = tv[k] / denom;
            out_i[tok * TOPK + k] = (float)ti[k];
        }
    }
    __syncthreads();

    // cooperative coalesced probs store: 64 tok x 16 float4
    for (int i = tid; i < BLK_TOK * 16; i += 256) {
        const int t  = i >> 4;
        const int e4 = (i & 15) << 2;
        const float* src = &lg[t * 65 + e4];
        *(float4*)&out_p[(size_t)(tok0 + t) * NEXP + e4] =
            make_float4(src[0], src[1], src[2], src[3]);
    }
}

// Repair: iterate compacted flagged-token list, recompute logits in fp64, rewrite w/i.
// 256 threads: expert = tid&63, d-quarter = tid>>6; LDS-reduce 4 partials.
__global__ __launch_bounds__(256)
void repair_kernel(const float* __restrict__ x, const float* __restrict__ W,
                   const int* __restrict__ cnt, const int* __restrict__ list,
                   float* __restrict__ out_w, float* __restrict__ out_i) {
    __shared__ float  xs[D_MODEL];   // 16 KB
    __shared__ double ls[4][NEXP];   // 2 KB
    const int tid = threadIdx.x;
    const int e   = tid & 63;
    const int w4  = tid >> 6;        // d-quarter 0..3
    const int n   = cnt[0];

    for (int i = blockIdx.x; i < n; i += gridDim.x) {
        const int tok = list[i];
        __syncthreads();             // protect xs reuse across iterations
        const float4* xsrc = (const float4*)(x + (size_t)tok * D_MODEL);
        for (int v = tid; v < D_MODEL / 4; v += 256)
            ((float4*)xs)[v] = xsrc[v];
        __syncthreads();

        const float* wrow = W + (size_t)e * D_MODEL + w4 * (D_MODEL / 4);
        const float* xrow = xs + w4 * (D_MODEL / 4);
        double s0 = 0., s1 = 0., s2 = 0., s3 = 0.;
        for (int d = 0; d < D_MODEL / 4; d += 4) {
            const float4 wv = *(const float4*)(wrow + d);
            const float4 xv = *(const float4*)(xrow + d);
            s0 += (double)xv.x * (double)wv.x;
            s1 += (double)xv.y * (double)wv.y;
            s2 += (double)xv.z * (double)wv.z;
            s3 += (double)xv.w * (double)wv.w;
        }
        ls[w4][e] = (s0 + s1) + (s2 + s3);
        __syncthreads();

        if (tid == 0) {
            double lsum[64];
            for (int k = 0; k < 64; ++k)
                lsum[k] = (ls[0][k] + ls[1][k]) + (ls[2][k] + ls[3][k]);
            double m = -1e300;
            for (int k = 0; k < 64; ++k) m = lsum[k] > m ? lsum[k] : m;
            double p[64], Z = 0.;
            for (int k = 0; k < 64; ++k) { p[k] = exp(lsum[k] - m); Z += p[k]; }
            for (int k = 0; k < 64; ++k) p[k] /= Z;

            double tv[8]; int ti[8];
            for (int k = 0; k < 8; ++k) { tv[k] = -1.; ti[k] = 0; }
            for (int k = 0; k < 64; ++k) {
                double v = p[k]; int idx = k;
                for (int u = 0; u < 8; ++u) {
                    const bool gt = v > tv[u];
                    const double nv = gt ? v : tv[u];
                    const int    ni = gt ? idx : ti[u];
                    const double ov = gt ? tv[u] : v;
                    const int    oi = gt ? ti[u] : idx;
                    tv[u] = nv; ti[u] = ni; v = ov; idx = oi;
                }
            }
            double s8 = 0.;
            for (int k = 0; k < 8; ++k) s8 += tv[k];
            const double denom = s8 + 1e-9;
            for (int k = 0; k < 8; ++k) {
                out_w[tok * TOPK + k] = (float)(tv[k] / denom);
                out_i[tok * TOPK + k] = (float)ti[k];
            }
        }
    }
}

extern "C" void kernel_launch(void* const* d_in, const int* in_sizes, int n_in,
                              void* d_out, int out_size, void* d_ws, size_t ws_size,
                              hipStream_t stream) {
    const float* x = (const float*)d_in[0];   // [4,4096,4096]
    const float* W = (const float*)d_in[1];   // [64,4096]

    // workspace layout: same ~1.07 MB footprint as all passing rounds
    unsigned short* W2 = (unsigned short*)d_ws;          // 1 MB (bf16 hi/lo)
    int* cnt  = (int*)(W2 + W2_USHORTS);                 // 1 int
    int* list = cnt + 1;                                 // up to 16384 ints

    float* out   = (float*)d_out;
    float* out_w = out;                       // [16384,8]
    float* out_i = out + NTOK * TOPK;         // [16384,8] (as float)
    float* out_p = out + 2 * NTOK * TOPK;     // [16384,64]; doubles as logit accumulator

    // transpose kernel also zeros out_p and cnt (no separate memsets)
    transpose_w_kernel<<<262144 / 256, 256, 0, stream>>>(W, W2, out_p, cnt);
    router_kernel<<<R_GRID, 256, 0, stream>>>(x, W2, out_p);
    finalize_kernel<<<NTOK / BLK_TOK, 256, 0, stream>>>(out_p, out_w, out_i, cnt, list);
    repair_kernel<<<256, 256, 0, stream>>>(x, W, cnt, list, out_w, out_i);
}